// Round 7
// baseline (227.978 us; speedup 1.0000x reference)
//
#include <hip/hip_runtime.h>

#define SEQ  2048
#define HID  128
#define NB   32
#define TILE 86            // owned output rows per block
#define GX   24            // 24*86 = 2064 >= 2048; grid 24*32 = 768 = exactly 3/CU
#define MROWS 96           // staged rows (6 MFMA row-tiles)
#define MSTR 97            // hT row stride (odd -> bank-conflict-free)

typedef float f2    __attribute__((ext_vector_type(2)));
typedef float f32x4 __attribute__((ext_vector_type(4)));
typedef short bf16x8 __attribute__((ext_vector_type(8)));
typedef unsigned u32x4 __attribute__((ext_vector_type(4)));

// split v into bf16 hi + bf16 lo (RNE both); v ~= hi + lo to ~16 mantissa bits
__device__ __forceinline__ void split_bf16(float v, short& h, short& l) {
  unsigned u = __float_as_uint(v);
  unsigned r = (u + 0x7fffu + ((u >> 16) & 1u)) >> 16;
  h = (short)r;
  const float hf = __uint_as_float(r << 16);
  const float lo = v - hf;
  unsigned u2 = __float_as_uint(lo);
  unsigned r2 = (u2 + 0x7fffu + ((u2 >> 16) & 1u)) >> 16;
  l = (short)r2;
}

// packed RNE bf16 conversion of a float pair: lo16 = bf16(a), hi16 = bf16(b).
__device__ __forceinline__ unsigned cvt_pk_bf16(float a, float b) {
  unsigned r;
  asm("v_cvt_pk_bf16_f32 %0, %1, %2" : "=v"(r) : "v"(a), "v"(b));
  return r;
}

// ---------------------------------------------------------------------------
// prep_kernel (merged fold + shuffle + counter init) — unchanged from R3.
//  blocks 0..31  (L=0): W' = enc_w2 @ gc1_w tile, split bf16 hi/lo, frags.
//  blocks 32..95 (L=1,2): split gc2_w / gc3_w directly into frags.
//  block 96: b' = enc_b2 @ gc1_w + gc1_b; zero per-batch arrival counters.
// ---------------------------------------------------------------------------
__global__ __launch_bounds__(256) void prep_kernel(
    const float* __restrict__ enc_w2, const float* __restrict__ enc_b2,
    const float* __restrict__ gc1_w, const float* __restrict__ gc1_b,
    const float* __restrict__ gc2_w, const float* __restrict__ gc3_w,
    short* __restrict__ Wf, float* __restrict__ bp, unsigned* __restrict__ cnt)
{
  const int tid = threadIdx.x;
  const int bid = blockIdx.x;

  if (bid == 96) {
    if (tid < 128) {
      float s = gc1_b[tid];
      for (int k = 0; k < 128; ++k) s = fmaf(enc_b2[k], gc1_w[k * 128 + tid], s);
      bp[tid] = s;
    }
    if (tid < NB) cnt[tid] = 0u;
    return;
  }

  const int L = bid >> 5, bx = bid & 31;
  short* hi = Wf + L * 32768;
  short* lo = hi + 16384;

  if (L == 0) {
    __shared__ float As[32 * 128];
    __shared__ float Bs[128 * 16];
    const int k0 = (bx >> 3) * 32, n0 = (bx & 7) * 16;
    for (int i = tid; i < 1024; i += 256)
      ((f32x4*)As)[i] = ((const f32x4*)(enc_w2 + k0 * 128))[i];
    for (int i = tid; i < 512; i += 256) {
      const int t = i >> 2, q = i & 3;
      ((f32x4*)Bs)[i] = *(const f32x4*)(gc1_w + t * 128 + n0 + q * 4);
    }
    __syncthreads();
    #pragma unroll
    for (int e = 0; e < 2; ++e) {
      const int f = tid + e * 256;
      const int l = f >> 3, j = f & 7;
      const float* ar = As + ((l >> 4) * 8 + j) * 128;
      const int nn = l & 15;
      float s0 = 0.f, s1 = 0.f, s2 = 0.f, s3 = 0.f;
      for (int t = 0; t < 128; t += 4) {
        s0 = fmaf(ar[t + 0], Bs[(t + 0) * 16 + nn], s0);
        s1 = fmaf(ar[t + 1], Bs[(t + 1) * 16 + nn], s1);
        s2 = fmaf(ar[t + 2], Bs[(t + 2) * 16 + nn], s2);
        s3 = fmaf(ar[t + 3], Bs[(t + 3) * 16 + nn], s3);
      }
      short h, lw;
      split_bf16((s0 + s1) + (s2 + s3), h, lw);
      hi[bx * 512 + f] = h; lo[bx * 512 + f] = lw;
    }
  } else {
    const float* __restrict__ SW = (L == 1) ? gc2_w : gc3_w;
    const int ks = bx >> 3, nt = bx & 7;
    for (int f = tid; f < 512; f += 256) {
      const int l = f >> 3, j = f & 7;
      const int k = ks * 32 + (l >> 4) * 8 + j;
      const int n = nt * 16 + (l & 15);
      short h, lw;
      split_bf16(SW[k * 128 + n], h, lw);
      hi[bx * 512 + f] = h; lo[bx * 512 + f] = lw;
    }
  }
}

// ---------------------------------------------------------------------------
// Fused enc1 -> [enc2*gc1 folded] -> gc2 -> gc3 -> pool -> (last block per
// batch) classifier.  MFMA bf16x3.
// GRID SHAPE (round-6 lesson): 768 blocks = exactly 3 blocks/CU (LDS ~52KB)
// -> no tail round (1152@4/CU had a half-empty second phase: measured occ
// 21% ~= half of nominal).  Block = 384 thr = 6 waves; wave w owns row-tile
// m = w*16..w*16+15 of 96 staged rows (s = s0-3+m), full nt range per wave
// (NO nt-split: R6 showed duplicated A-assembly costs more than occupancy
// gains).  Activations in transposed LDS hT[k][m], stride 97 (odd).
// launch_bounds(384,5): VGPR cap ~102 vs ~80 natural -> no spill (R5 lesson),
// allows 18 waves/CU (SIMDs at 5,5,4,4).
// Handoff: agent-scope plain stores + per-thread vmcnt drain + ONE RELAXED
// counter RMW (acq_rel = L2 wb/inv, evicted hot Wfrag — R2 lesson); last
// block per batch reads partials agent-scope, runs classifier inline.
// Validity: t1 ok m[0,95]&inseq -> h1 [1,94] -> t2 [1,94] -> h2 [2,93]
// -> t3 [2,93] -> pooled m in [3,88] need t3[m-1..m+1] in [2,89]. OK.
// ---------------------------------------------------------------------------
__global__ __launch_bounds__(384, 5) void fused_kernel(
    const float* __restrict__ x,
    const float* __restrict__ enc_w1, const float* __restrict__ enc_b1,
    const short* __restrict__ Wf, const float* __restrict__ bp,
    const float* __restrict__ gc2_b, const float* __restrict__ gc3_b,
    float* __restrict__ partial, unsigned* __restrict__ cnt,
    const float* __restrict__ cls_w1, const float* __restrict__ cls_b1,
    const float* __restrict__ cls_w2, const float* __restrict__ cls_b2,
    float* __restrict__ out)
{
  __shared__ float hT[HID * MSTR];   // 49664 B, [k][m]
  __shared__ float xsps[576];        // x-stage (96x6) in enc1; psum[384] later
  __shared__ int lastf;

  const int tid  = threadIdx.x;
  const int lane = tid & 63;
  const int w    = tid >> 6;            // wave id 0..5
  const int gxb  = blockIdx.x, b = blockIdx.y;
  const int s0   = gxb * TILE;
  const bf16x8* Bf = (const bf16x8*)Wf;

  // ---------------- stage x rows (96 x 6 floats as 288 f2) ----------------
  for (int i = tid; i < 288; i += 384) {
    const int row = i / 3, p = i - row * 3;
    const int s = s0 - 3 + row;
    f2 v = {0.f, 0.f};
    if (s >= 0 && s < SEQ)
      v = *(const f2*)(x + ((long long)b * SEQ + s) * 6 + p * 2);
    ((f2*)xsps)[i] = v;
  }
  __syncthreads();

  // ---------------- enc1: thread = (col c, row-group g of 32) -------------
  {
    const int c = tid & 127, g = tid >> 7;       // g = 0..2
    float w1r[6];
    #pragma unroll
    for (int k = 0; k < 6; ++k) w1r[k] = enc_w1[k * HID + c];
    const float b1r = enc_b1[c];
    #pragma unroll 4
    for (int r = 0; r < 32; ++r) {
      const int m = g * 32 + r;
      const float* xr = &xsps[m * 6];            // broadcast across c-threads
      float a = b1r;
      #pragma unroll
      for (int k = 0; k < 6; ++k) a = fmaf(xr[k], w1r[k], a);
      hT[c * MSTR + m] = fmaxf(a, 0.f);
    }
  }
  __syncthreads();

  // ---------------- 3 MFMA layers ----------------
  const int mt   = w * 16 + (lane & 15);       // A-frag target row (0..95)
  const int koct = (lane >> 4) * 8;            // A-frag k-octet base
  const int stt  = s0 - 3 + mt;
  const float invdA = (stt == 0 || stt == SEQ - 1) ? (1.0f / (2.0f + 1e-8f))
                                                   : (1.0f / (3.0f + 1e-8f));
  const int mm = (mt == 0) ? 0 : mt - 1;
  const int mp = (mt == MROWS - 1) ? (MROWS - 1) : mt + 1;

  #pragma unroll 1
  for (int L = 0; L < 3; ++L) {
    const bf16x8* BhL = Bf + L * 4096;
    const bf16x8* BlL = BhL + 2048;
    const float* bias = (L == 0) ? bp : (L == 1) ? gc2_b : gc3_b;

    f32x4 acc_[8];
    #pragma unroll
    for (int nt = 0; nt < 8; ++nt) acc_[nt] = (f32x4){0.f, 0.f, 0.f, 0.f};

    #pragma unroll 1
    for (int ks = 0; ks < 4; ++ks) {
      // B-frags first (VMEM latency hides behind A assembly)
      const int fb = ks * 512 + lane;
      bf16x8 bh[8], bl[8];
      #pragma unroll
      for (int nt = 0; nt < 8; ++nt) {
        bh[nt] = BhL[fb + nt * 64];
        bl[nt] = BlL[fb + nt * 64];
      }
      // A-frag: read hT (agg+relu for L>0), cvt_pk pair-split hi/lo
      bf16x8 ah, al;
      {
        const float* pa = &hT[(ks * 32 + koct) * MSTR];
        float v[8];
        #pragma unroll
        for (int j = 0; j < 8; ++j) {
          if (L == 0) {
            v[j] = pa[j * MSTR + mt];
          } else {
            const float t = (pa[j * MSTR + mm] + pa[j * MSTR + mt] +
                             pa[j * MSTR + mp]) * invdA;
            v[j] = fmaxf(t, 0.f);
          }
        }
        u32x4 hv, lv;
        #pragma unroll
        for (int q = 0; q < 4; ++q) {
          const unsigned hp = cvt_pk_bf16(v[2 * q], v[2 * q + 1]);
          const float h0 = __uint_as_float(hp << 16);
          const float h1 = __uint_as_float(hp & 0xffff0000u);
          hv[q] = hp;
          lv[q] = cvt_pk_bf16(v[2 * q] - h0, v[2 * q + 1] - h1);
        }
        ah = __builtin_bit_cast(bf16x8, hv);
        al = __builtin_bit_cast(bf16x8, lv);
      }
      #pragma unroll
      for (int nt = 0; nt < 8; ++nt) {
        acc_[nt] = __builtin_amdgcn_mfma_f32_16x16x32_bf16(ah, bh[nt], acc_[nt], 0, 0, 0);
        acc_[nt] = __builtin_amdgcn_mfma_f32_16x16x32_bf16(ah, bl[nt], acc_[nt], 0, 0, 0);
        acc_[nt] = __builtin_amdgcn_mfma_f32_16x16x32_bf16(al, bh[nt], acc_[nt], 0, 0, 0);
      }
    }
    __syncthreads();   // all hT reads of this layer done

    // epilogue: t = inseq ? acc + bias : 0 -> hT[n][m]  (C/D layout scatter)
    {
      const int n0 = lane & 15;
      const int mrow0 = w * 16 + (lane >> 4) * 4;
      #pragma unroll
      for (int nt = 0; nt < 8; ++nt) {
        const float bn = bias[nt * 16 + n0];
        float* pw = &hT[(nt * 16 + n0) * MSTR];
        #pragma unroll
        for (int r = 0; r < 4; ++r) {
          const int m = mrow0 + r;
          const int s = s0 - 3 + m;
          const bool vld = (s >= 0 && s < SEQ);
          pw[m] = vld ? (acc_[nt][r] + bn) : 0.f;
        }
      }
    }
    __syncthreads();   // publish t for next layer / pool
  }

  // ---------------- pool: h3 = relu(agg(t3)); sum owned rows ----------------
  {
    const int c = tid & 127, q = tid >> 7;   // col, row-third 0..2
    float ps = 0.f;
    const float* pc = &hT[c * MSTR];
    #pragma unroll 1
    for (int r = q; r < TILE; r += 3) {
      const int m = 3 + r;
      const int s = s0 + r;
      if (s < SEQ) {
        const float invd = (s == 0 || s == SEQ - 1) ? (1.0f / (2.0f + 1e-8f))
                                                    : (1.0f / (3.0f + 1e-8f));
        ps += fmaxf((pc[m - 1] + pc[m] + pc[m + 1]) * invd, 0.f);
      }
    }
    xsps[tid] = ps;                          // psum lives in xsps now
  }
  __syncthreads();

  // ---------------- publish partial (agent-scope stores, no contention) ----
  if (tid < 128) {
    __hip_atomic_store(&partial[((long long)b * GX + gxb) * HID + tid],
                       xsps[tid] + xsps[tid + 128] + xsps[tid + 256],
                       __ATOMIC_RELAXED, __HIP_MEMORY_SCOPE_AGENT);
  }
  // each thread drains its own store acks (coherent point) before barrier
  asm volatile("s_waitcnt vmcnt(0)" ::: "memory");
  __syncthreads();
  if (tid == 0) {
    // RELAXED on purpose — see header comment (no L2 writeback/invalidate).
    const unsigned old = __hip_atomic_fetch_add(&cnt[b], 1u, __ATOMIC_RELAXED,
                                                __HIP_MEMORY_SCOPE_AGENT);
    lastf = (old == GX - 1) ? 1 : 0;
  }
  __syncthreads();
  if (!lastf) return;

  // ---------------- classifier (last block of batch b only) ----------------
  if (tid < 128) {
    float a = 0.f;
    #pragma unroll
    for (int g = 0; g < GX; ++g)
      a += __hip_atomic_load(&partial[((long long)b * GX + g) * HID + tid],
                             __ATOMIC_RELAXED, __HIP_MEMORY_SCOPE_AGENT);
    xsps[tid] = a * (1.0f / 2048.0f);
  }
  __syncthreads();
  if (tid < 64) {
    float h = cls_b1[tid];
    for (int k = 0; k < 128; ++k) h = fmaf(xsps[k], cls_w1[k * 64 + tid], h);
    xsps[128 + tid] = fmaxf(h, 0.f);
  }
  __syncthreads();
  if (tid < 3) {
    float o = cls_b2[tid];
    for (int k = 0; k < 64; ++k) o = fmaf(xsps[128 + k], cls_w2[k * 3 + tid], o);
    out[b * 3 + tid] = o;
  }
}

extern "C" void kernel_launch(void* const* d_in, const int* in_sizes, int n_in,
                              void* d_out, int out_size, void* d_ws, size_t ws_size,
                              hipStream_t stream) {
  (void)in_sizes; (void)n_in; (void)out_size; (void)ws_size;
  const float* x      = (const float*)d_in[0];
  const float* enc_w1 = (const float*)d_in[1];
  const float* enc_b1 = (const float*)d_in[2];
  const float* enc_w2 = (const float*)d_in[3];
  const float* enc_b2 = (const float*)d_in[4];
  const float* gc1_w  = (const float*)d_in[5];
  const float* gc1_b  = (const float*)d_in[6];
  const float* gc2_w  = (const float*)d_in[7];
  const float* gc2_b  = (const float*)d_in[8];
  const float* gc3_w  = (const float*)d_in[9];
  const float* gc3_b  = (const float*)d_in[10];
  const float* cls_w1 = (const float*)d_in[11];
  const float* cls_b1 = (const float*)d_in[12];
  const float* cls_w2 = (const float*)d_in[13];
  const float* cls_b2 = (const float*)d_in[14];

  // workspace layout (rewritten fully every launch — ws is re-poisoned)
  float* bpv     = (float*)d_ws;                     // 128 f32
  short* Wfrag   = (short*)(bpv + 128);              // 3 * 2 * 16384 bf16
  float* partial = (float*)(Wfrag + 3 * 2 * 16384);  // NB*GX*HID f32 (all slots rewritten)
  unsigned* cntb = (unsigned*)(partial + (long long)NB * GX * HID);  // NB u32 (zeroed by prep)

  prep_kernel<<<dim3(97), 256, 0, stream>>>(enc_w2, enc_b2, gc1_w, gc1_b,
                                            gc2_w, gc3_w, Wfrag, bpv, cntb);
  fused_kernel<<<dim3(GX, NB), 384, 0, stream>>>(
      x, enc_w1, enc_b1, Wfrag, bpv, gc2_b, gc3_b, partial, cntb,
      cls_w1, cls_b1, cls_w2, cls_b2, (float*)d_out);
}

// Round 8
// 156.644 us; speedup vs baseline: 1.4554x; 1.4554x over previous
//
#include <hip/hip_runtime.h>

#define SEQ  2048
#define HID  128
#define NB   32
#define TILE 86            // owned output rows per block
#define GX   24            // 24*86 = 2064 >= 2048; grid 24*32 = 768 = exactly 3/CU
#define MROWS 96           // staged rows (6 MFMA row-tiles)
#define MSTR 97            // hT row stride (odd -> bank-conflict-free)

typedef float f2    __attribute__((ext_vector_type(2)));
typedef float f32x4 __attribute__((ext_vector_type(4)));
typedef short bf16x8 __attribute__((ext_vector_type(8)));
typedef unsigned u32x4 __attribute__((ext_vector_type(4)));

// split v into bf16 hi + bf16 lo (RNE both); v ~= hi + lo to ~16 mantissa bits
__device__ __forceinline__ void split_bf16(float v, short& h, short& l) {
  unsigned u = __float_as_uint(v);
  unsigned r = (u + 0x7fffu + ((u >> 16) & 1u)) >> 16;
  h = (short)r;
  const float hf = __uint_as_float(r << 16);
  const float lo = v - hf;
  unsigned u2 = __float_as_uint(lo);
  unsigned r2 = (u2 + 0x7fffu + ((u2 >> 16) & 1u)) >> 16;
  l = (short)r2;
}

// packed RNE bf16 conversion of a float pair: lo16 = bf16(a), hi16 = bf16(b).
__device__ __forceinline__ unsigned cvt_pk_bf16(float a, float b) {
  unsigned r;
  asm("v_cvt_pk_bf16_f32 %0, %1, %2" : "=v"(r) : "v"(a), "v"(b));
  return r;
}

// ---------------------------------------------------------------------------
// prep_kernel (merged fold + shuffle + counter init) — unchanged from R3.
//  blocks 0..31  (L=0): W' = enc_w2 @ gc1_w tile, split bf16 hi/lo, frags.
//  blocks 32..95 (L=1,2): split gc2_w / gc3_w directly into frags.
//  block 96: b' = enc_b2 @ gc1_w + gc1_b; zero per-batch arrival counters.
// ---------------------------------------------------------------------------
__global__ __launch_bounds__(256) void prep_kernel(
    const float* __restrict__ enc_w2, const float* __restrict__ enc_b2,
    const float* __restrict__ gc1_w, const float* __restrict__ gc1_b,
    const float* __restrict__ gc2_w, const float* __restrict__ gc3_w,
    short* __restrict__ Wf, float* __restrict__ bp, unsigned* __restrict__ cnt)
{
  const int tid = threadIdx.x;
  const int bid = blockIdx.x;

  if (bid == 96) {
    if (tid < 128) {
      float s = gc1_b[tid];
      for (int k = 0; k < 128; ++k) s = fmaf(enc_b2[k], gc1_w[k * 128 + tid], s);
      bp[tid] = s;
    }
    if (tid < NB) cnt[tid] = 0u;
    return;
  }

  const int L = bid >> 5, bx = bid & 31;
  short* hi = Wf + L * 32768;
  short* lo = hi + 16384;

  if (L == 0) {
    __shared__ float As[32 * 128];
    __shared__ float Bs[128 * 16];
    const int k0 = (bx >> 3) * 32, n0 = (bx & 7) * 16;
    for (int i = tid; i < 1024; i += 256)
      ((f32x4*)As)[i] = ((const f32x4*)(enc_w2 + k0 * 128))[i];
    for (int i = tid; i < 512; i += 256) {
      const int t = i >> 2, q = i & 3;
      ((f32x4*)Bs)[i] = *(const f32x4*)(gc1_w + t * 128 + n0 + q * 4);
    }
    __syncthreads();
    #pragma unroll
    for (int e = 0; e < 2; ++e) {
      const int f = tid + e * 256;
      const int l = f >> 3, j = f & 7;
      const float* ar = As + ((l >> 4) * 8 + j) * 128;
      const int nn = l & 15;
      float s0 = 0.f, s1 = 0.f, s2 = 0.f, s3 = 0.f;
      for (int t = 0; t < 128; t += 4) {
        s0 = fmaf(ar[t + 0], Bs[(t + 0) * 16 + nn], s0);
        s1 = fmaf(ar[t + 1], Bs[(t + 1) * 16 + nn], s1);
        s2 = fmaf(ar[t + 2], Bs[(t + 2) * 16 + nn], s2);
        s3 = fmaf(ar[t + 3], Bs[(t + 3) * 16 + nn], s3);
      }
      short h, lw;
      split_bf16((s0 + s1) + (s2 + s3), h, lw);
      hi[bx * 512 + f] = h; lo[bx * 512 + f] = lw;
    }
  } else {
    const float* __restrict__ SW = (L == 1) ? gc2_w : gc3_w;
    const int ks = bx >> 3, nt = bx & 7;
    for (int f = tid; f < 512; f += 256) {
      const int l = f >> 3, j = f & 7;
      const int k = ks * 32 + (l >> 4) * 8 + j;
      const int n = nt * 16 + (l & 15);
      short h, lw;
      split_bf16(SW[k * 128 + n], h, lw);
      hi[bx * 512 + f] = h; lo[bx * 512 + f] = lw;
    }
  }
}

// ---------------------------------------------------------------------------
// Fused enc1 -> [enc2*gc1 folded] -> gc2 -> gc3 -> pool -> (last block per
// batch) classifier.  MFMA bf16x3.
// GRID SHAPE (R6/R7): 768 blocks = exactly 3 blocks/CU (LDS ~52KB) -> no
// tail round.  Block = 384 thr = 6 waves; wave w owns row-tile m = w*16..
// +15 of 96 staged rows, full nt range per wave.  hT[k][m], stride 97.
// REGISTER BUDGET (R7 lesson): launch_bounds(384,5) caps ~96-102 total regs
// per wave; bh[8]+bl[8] upfront (64 VGPR) + 32 AGPR acc + addressing = ~112
// -> spilled 102MB/dispatch.  Fix: B-frag prefetch in TWO HALVES of 4
// (32 VGPR, reused) -> demand ~88 total, fits the 5-wave cap.  Half-2 loads
// overlap half-1 MFMAs; half-1 loads overlap previous ks MFMA tail.
// Handoff: agent-scope plain stores + per-thread vmcnt drain + ONE RELAXED
// counter RMW (acq_rel = L2 wb/inv evicting hot Wfrag — R2 lesson); last
// block per batch reads partials agent-scope, runs classifier inline.
// Validity: t1 ok m[0,95]&inseq -> h1 [1,94] -> t2 [1,94] -> h2 [2,93]
// -> t3 [2,93] -> pooled m in [3,88] need t3[m-1..m+1] in [2,89]. OK.
// ---------------------------------------------------------------------------
__global__ __launch_bounds__(384, 5) void fused_kernel(
    const float* __restrict__ x,
    const float* __restrict__ enc_w1, const float* __restrict__ enc_b1,
    const short* __restrict__ Wf, const float* __restrict__ bp,
    const float* __restrict__ gc2_b, const float* __restrict__ gc3_b,
    float* __restrict__ partial, unsigned* __restrict__ cnt,
    const float* __restrict__ cls_w1, const float* __restrict__ cls_b1,
    const float* __restrict__ cls_w2, const float* __restrict__ cls_b2,
    float* __restrict__ out)
{
  __shared__ float hT[HID * MSTR];   // 49664 B, [k][m]
  __shared__ float xsps[576];        // x-stage (96x6) in enc1; psum[384] later
  __shared__ int lastf;

  const int tid  = threadIdx.x;
  const int lane = tid & 63;
  const int w    = tid >> 6;            // wave id 0..5
  const int gxb  = blockIdx.x, b = blockIdx.y;
  const int s0   = gxb * TILE;
  const bf16x8* Bf = (const bf16x8*)Wf;

  // ---------------- stage x rows (96 x 6 floats as 288 f2) ----------------
  for (int i = tid; i < 288; i += 384) {
    const int row = i / 3, p = i - row * 3;
    const int s = s0 - 3 + row;
    f2 v = {0.f, 0.f};
    if (s >= 0 && s < SEQ)
      v = *(const f2*)(x + ((long long)b * SEQ + s) * 6 + p * 2);
    ((f2*)xsps)[i] = v;
  }
  __syncthreads();

  // ---------------- enc1: thread = (col c, row-group g of 32) -------------
  {
    const int c = tid & 127, g = tid >> 7;       // g = 0..2
    float w1r[6];
    #pragma unroll
    for (int k = 0; k < 6; ++k) w1r[k] = enc_w1[k * HID + c];
    const float b1r = enc_b1[c];
    #pragma unroll 4
    for (int r = 0; r < 32; ++r) {
      const int m = g * 32 + r;
      const float* xr = &xsps[m * 6];            // broadcast across c-threads
      float a = b1r;
      #pragma unroll
      for (int k = 0; k < 6; ++k) a = fmaf(xr[k], w1r[k], a);
      hT[c * MSTR + m] = fmaxf(a, 0.f);
    }
  }
  __syncthreads();

  // ---------------- 3 MFMA layers ----------------
  const int mt   = w * 16 + (lane & 15);       // A-frag target row (0..95)
  const int koct = (lane >> 4) * 8;            // A-frag k-octet base
  const int stt  = s0 - 3 + mt;
  const float invdA = (stt == 0 || stt == SEQ - 1) ? (1.0f / (2.0f + 1e-8f))
                                                   : (1.0f / (3.0f + 1e-8f));
  const int mm = (mt == 0) ? 0 : mt - 1;
  const int mp = (mt == MROWS - 1) ? (MROWS - 1) : mt + 1;

  #pragma unroll 1
  for (int L = 0; L < 3; ++L) {
    const bf16x8* BhL = Bf + L * 4096;
    const bf16x8* BlL = BhL + 2048;
    const float* bias = (L == 0) ? bp : (L == 1) ? gc2_b : gc3_b;

    f32x4 acc_[8];
    #pragma unroll
    for (int nt = 0; nt < 8; ++nt) acc_[nt] = (f32x4){0.f, 0.f, 0.f, 0.f};

    #pragma unroll 1
    for (int ks = 0; ks < 4; ++ks) {
      const int fb = ks * 512 + lane;
      // ---- half 1: B-frags nt 0..3 (32 VGPR, reused for half 2) ----
      bf16x8 bh[4], bl[4];
      #pragma unroll
      for (int i = 0; i < 4; ++i) {
        bh[i] = BhL[fb + i * 64];
        bl[i] = BlL[fb + i * 64];
      }
      // A-frag: read hT (agg+relu for L>0), cvt_pk pair-split hi/lo
      bf16x8 ah, al;
      {
        const float* pa = &hT[(ks * 32 + koct) * MSTR];
        float v[8];
        #pragma unroll
        for (int j = 0; j < 8; ++j) {
          if (L == 0) {
            v[j] = pa[j * MSTR + mt];
          } else {
            const float t = (pa[j * MSTR + mm] + pa[j * MSTR + mt] +
                             pa[j * MSTR + mp]) * invdA;
            v[j] = fmaxf(t, 0.f);
          }
        }
        u32x4 hv, lv;
        #pragma unroll
        for (int q = 0; q < 4; ++q) {
          const unsigned hp = cvt_pk_bf16(v[2 * q], v[2 * q + 1]);
          const float h0 = __uint_as_float(hp << 16);
          const float h1 = __uint_as_float(hp & 0xffff0000u);
          hv[q] = hp;
          lv[q] = cvt_pk_bf16(v[2 * q] - h0, v[2 * q + 1] - h1);
        }
        ah = __builtin_bit_cast(bf16x8, hv);
        al = __builtin_bit_cast(bf16x8, lv);
      }
      #pragma unroll
      for (int i = 0; i < 4; ++i) {
        acc_[i] = __builtin_amdgcn_mfma_f32_16x16x32_bf16(ah, bh[i], acc_[i], 0, 0, 0);
        acc_[i] = __builtin_amdgcn_mfma_f32_16x16x32_bf16(ah, bl[i], acc_[i], 0, 0, 0);
        acc_[i] = __builtin_amdgcn_mfma_f32_16x16x32_bf16(al, bh[i], acc_[i], 0, 0, 0);
      }
      // ---- half 2: B-frags nt 4..7 (loads overlap half-1 MFMAs above) ----
      bf16x8 ch[4], cl[4];
      #pragma unroll
      for (int i = 0; i < 4; ++i) {
        ch[i] = BhL[fb + (i + 4) * 64];
        cl[i] = BlL[fb + (i + 4) * 64];
      }
      #pragma unroll
      for (int i = 0; i < 4; ++i) {
        acc_[i + 4] = __builtin_amdgcn_mfma_f32_16x16x32_bf16(ah, ch[i], acc_[i + 4], 0, 0, 0);
        acc_[i + 4] = __builtin_amdgcn_mfma_f32_16x16x32_bf16(ah, cl[i], acc_[i + 4], 0, 0, 0);
        acc_[i + 4] = __builtin_amdgcn_mfma_f32_16x16x32_bf16(al, ch[i], acc_[i + 4], 0, 0, 0);
      }
    }
    __syncthreads();   // all hT reads of this layer done

    // epilogue: t = inseq ? acc + bias : 0 -> hT[n][m]  (C/D layout scatter)
    {
      const int n0 = lane & 15;
      const int mrow0 = w * 16 + (lane >> 4) * 4;
      #pragma unroll
      for (int nt = 0; nt < 8; ++nt) {
        const float bn = bias[nt * 16 + n0];
        float* pw = &hT[(nt * 16 + n0) * MSTR];
        #pragma unroll
        for (int r = 0; r < 4; ++r) {
          const int m = mrow0 + r;
          const int s = s0 - 3 + m;
          const bool vld = (s >= 0 && s < SEQ);
          pw[m] = vld ? (acc_[nt][r] + bn) : 0.f;
        }
      }
    }
    __syncthreads();   // publish t for next layer / pool
  }

  // ---------------- pool: h3 = relu(agg(t3)); sum owned rows ----------------
  {
    const int c = tid & 127, q = tid >> 7;   // col, row-third 0..2
    float ps = 0.f;
    const float* pc = &hT[c * MSTR];
    #pragma unroll 1
    for (int r = q; r < TILE; r += 3) {
      const int m = 3 + r;
      const int s = s0 + r;
      if (s < SEQ) {
        const float invd = (s == 0 || s == SEQ - 1) ? (1.0f / (2.0f + 1e-8f))
                                                    : (1.0f / (3.0f + 1e-8f));
        ps += fmaxf((pc[m - 1] + pc[m] + pc[m + 1]) * invd, 0.f);
      }
    }
    xsps[tid] = ps;                          // psum lives in xsps now
  }
  __syncthreads();

  // ---------------- publish partial (agent-scope stores, no contention) ----
  if (tid < 128) {
    __hip_atomic_store(&partial[((long long)b * GX + gxb) * HID + tid],
                       xsps[tid] + xsps[tid + 128] + xsps[tid + 256],
                       __ATOMIC_RELAXED, __HIP_MEMORY_SCOPE_AGENT);
  }
  // each thread drains its own store acks (coherent point) before barrier
  asm volatile("s_waitcnt vmcnt(0)" ::: "memory");
  __syncthreads();
  if (tid == 0) {
    // RELAXED on purpose — see header comment (no L2 writeback/invalidate).
    const unsigned old = __hip_atomic_fetch_add(&cnt[b], 1u, __ATOMIC_RELAXED,
                                                __HIP_MEMORY_SCOPE_AGENT);
    lastf = (old == GX - 1) ? 1 : 0;
  }
  __syncthreads();
  if (!lastf) return;

  // ---------------- classifier (last block of batch b only) ----------------
  if (tid < 128) {
    float a = 0.f;
    #pragma unroll
    for (int g = 0; g < GX; ++g)
      a += __hip_atomic_load(&partial[((long long)b * GX + g) * HID + tid],
                             __ATOMIC_RELAXED, __HIP_MEMORY_SCOPE_AGENT);
    xsps[tid] = a * (1.0f / 2048.0f);
  }
  __syncthreads();
  if (tid < 64) {
    float h = cls_b1[tid];
    for (int k = 0; k < 128; ++k) h = fmaf(xsps[k], cls_w1[k * 64 + tid], h);
    xsps[128 + tid] = fmaxf(h, 0.f);
  }
  __syncthreads();
  if (tid < 3) {
    float o = cls_b2[tid];
    for (int k = 0; k < 64; ++k) o = fmaf(xsps[128 + k], cls_w2[k * 3 + tid], o);
    out[b * 3 + tid] = o;
  }
}

extern "C" void kernel_launch(void* const* d_in, const int* in_sizes, int n_in,
                              void* d_out, int out_size, void* d_ws, size_t ws_size,
                              hipStream_t stream) {
  (void)in_sizes; (void)n_in; (void)out_size; (void)ws_size;
  const float* x      = (const float*)d_in[0];
  const float* enc_w1 = (const float*)d_in[1];
  const float* enc_b1 = (const float*)d_in[2];
  const float* enc_w2 = (const float*)d_in[3];
  const float* enc_b2 = (const float*)d_in[4];
  const float* gc1_w  = (const float*)d_in[5];
  const float* gc1_b  = (const float*)d_in[6];
  const float* gc2_w  = (const float*)d_in[7];
  const float* gc2_b  = (const float*)d_in[8];
  const float* gc3_w  = (const float*)d_in[9];
  const float* gc3_b  = (const float*)d_in[10];
  const float* cls_w1 = (const float*)d_in[11];
  const float* cls_b1 = (const float*)d_in[12];
  const float* cls_w2 = (const float*)d_in[13];
  const float* cls_b2 = (const float*)d_in[14];

  // workspace layout (rewritten fully every launch — ws is re-poisoned)
  float* bpv     = (float*)d_ws;                     // 128 f32
  short* Wfrag   = (short*)(bpv + 128);              // 3 * 2 * 16384 bf16
  float* partial = (float*)(Wfrag + 3 * 2 * 16384);  // NB*GX*HID f32 (all slots rewritten)
  unsigned* cntb = (unsigned*)(partial + (long long)NB * GX * HID);  // NB u32 (zeroed by prep)

  prep_kernel<<<dim3(97), 256, 0, stream>>>(enc_w2, enc_b2, gc1_w, gc1_b,
                                            gc2_w, gc3_w, Wfrag, bpv, cntb);
  fused_kernel<<<dim3(GX, NB), 384, 0, stream>>>(
      x, enc_w1, enc_b1, Wfrag, bpv, gc2_b, gc3_b, partial, cntb,
      cls_w1, cls_b1, cls_w2, cls_b2, (float*)d_out);
}

// Round 9
// 138.969 us; speedup vs baseline: 1.6405x; 1.1272x over previous
//
#include <hip/hip_runtime.h>

#define SEQ  2048
#define HID  128
#define NB   32
#define TILE 58            // owned output rows per block
#define GX   36            // ceil(2048/58)
#define MSTR 67            // hT row stride: hT[k][slot], slot = m+1, m=0..63; slots 0,65 = guard
#define SLOT(m) ((m) + 1)

typedef float f2    __attribute__((ext_vector_type(2)));
typedef float f32x4 __attribute__((ext_vector_type(4)));
typedef short bf16x8 __attribute__((ext_vector_type(8)));
typedef unsigned u32x4 __attribute__((ext_vector_type(4)));

// split v into bf16 hi + bf16 lo (RNE both); v ~= hi + lo to ~16 mantissa bits
__device__ __forceinline__ void split_bf16(float v, short& h, short& l) {
  unsigned u = __float_as_uint(v);
  unsigned r = (u + 0x7fffu + ((u >> 16) & 1u)) >> 16;
  h = (short)r;
  const float hf = __uint_as_float(r << 16);
  const float lo = v - hf;
  unsigned u2 = __float_as_uint(lo);
  unsigned r2 = (u2 + 0x7fffu + ((u2 >> 16) & 1u)) >> 16;
  l = (short)r2;
}

// packed RNE bf16 conversion of a float pair: lo16 = bf16(a), hi16 = bf16(b).
__device__ __forceinline__ unsigned cvt_pk_bf16(float a, float b) {
  unsigned r;
  asm("v_cvt_pk_bf16_f32 %0, %1, %2" : "=v"(r) : "v"(a), "v"(b));
  return r;
}

// ---------------------------------------------------------------------------
// prep_kernel (merged fold + shuffle + counter init) — unchanged since R3.
//  blocks 0..31  (L=0): W' = enc_w2 @ gc1_w tile, split bf16 hi/lo, frags.
//  blocks 32..95 (L=1,2): split gc2_w / gc3_w directly into frags.
//  block 96: b' = enc_b2 @ gc1_w + gc1_b; zero per-batch arrival counters.
// ---------------------------------------------------------------------------
__global__ __launch_bounds__(256) void prep_kernel(
    const float* __restrict__ enc_w2, const float* __restrict__ enc_b2,
    const float* __restrict__ gc1_w, const float* __restrict__ gc1_b,
    const float* __restrict__ gc2_w, const float* __restrict__ gc3_w,
    short* __restrict__ Wf, float* __restrict__ bp, unsigned* __restrict__ cnt)
{
  const int tid = threadIdx.x;
  const int bid = blockIdx.x;

  if (bid == 96) {
    if (tid < 128) {
      float s = gc1_b[tid];
      for (int k = 0; k < 128; ++k) s = fmaf(enc_b2[k], gc1_w[k * 128 + tid], s);
      bp[tid] = s;
    }
    if (tid < NB) cnt[tid] = 0u;
    return;
  }

  const int L = bid >> 5, bx = bid & 31;
  short* hi = Wf + L * 32768;
  short* lo = hi + 16384;

  if (L == 0) {
    __shared__ float As[32 * 128];
    __shared__ float Bs[128 * 16];
    const int k0 = (bx >> 3) * 32, n0 = (bx & 7) * 16;
    for (int i = tid; i < 1024; i += 256)
      ((f32x4*)As)[i] = ((const f32x4*)(enc_w2 + k0 * 128))[i];
    for (int i = tid; i < 512; i += 256) {
      const int t = i >> 2, q = i & 3;
      ((f32x4*)Bs)[i] = *(const f32x4*)(gc1_w + t * 128 + n0 + q * 4);
    }
    __syncthreads();
    #pragma unroll
    for (int e = 0; e < 2; ++e) {
      const int f = tid + e * 256;
      const int l = f >> 3, j = f & 7;
      const float* ar = As + ((l >> 4) * 8 + j) * 128;
      const int nn = l & 15;
      float s0 = 0.f, s1 = 0.f, s2 = 0.f, s3 = 0.f;
      for (int t = 0; t < 128; t += 4) {
        s0 = fmaf(ar[t + 0], Bs[(t + 0) * 16 + nn], s0);
        s1 = fmaf(ar[t + 1], Bs[(t + 1) * 16 + nn], s1);
        s2 = fmaf(ar[t + 2], Bs[(t + 2) * 16 + nn], s2);
        s3 = fmaf(ar[t + 3], Bs[(t + 3) * 16 + nn], s3);
      }
      short h, lw;
      split_bf16((s0 + s1) + (s2 + s3), h, lw);
      hi[bx * 512 + f] = h; lo[bx * 512 + f] = lw;
    }
  } else {
    const float* __restrict__ SW = (L == 1) ? gc2_w : gc3_w;
    const int ks = bx >> 3, nt = bx & 7;
    for (int f = tid; f < 512; f += 256) {
      const int l = f >> 3, j = f & 7;
      const int k = ks * 32 + (l >> 4) * 8 + j;
      const int n = nt * 16 + (l & 15);
      short h, lw;
      split_bf16(SW[k * 128 + n], h, lw);
      hi[bx * 512 + f] = h; lo[bx * 512 + f] = lw;
    }
  }
}

// ---------------------------------------------------------------------------
// Fused enc1 -> [enc2*gc1 folded] -> gc2 -> gc3 -> pool -> (last block per
// batch) classifier.  MFMA bf16x3 — R3 structure (best measured: 57.8us).
// Block = (58-row seq tile, batch), 256 thr = 4 waves; wave w owns rows
// m = w*16 .. w*16+15 of the 64 staged rows (s = s0-3+m).
// hT layout: row m lives at slot m+1 (stride 67); slots 0 and 65 are ZEROED
// GUARD ROWS, so the tridiag-agg neighbor reads are the UNIFORM immediate
// offsets base+{0,4,8} for every lane — no per-lane edge clamp / cndmask
// chains (this round's change).  Guard slots only feed halo rows mt=0/63,
// which the validity telescoping excludes from owned output; zeroing them
// prevents NaN propagation from uninitialized LDS.
// Register budget (R4-R8 lessons): arch+acc <= 128 total keeps 4 waves/SIMD;
// this loop is ~112.  No launch_bounds cap beyond block size; no register
// double-buffering; no nt-split (all 4 waves load the same B-frags, that's
// fine at 4 blocks/CU).
// Handoff (R1/R2 lessons): agent-scope plain stores + per-thread vmcnt
// drain + ONE RELAXED counter RMW (acq_rel = L2 wb/inv evicting hot Wfrag);
// last block per batch reads partials agent-scope, classifier inline.
// Validity telescoping: t1 ok m in [0,63]&inseq -> h1 [1,62] -> h2 [2,61]
// -> t3 ok [2,61] -> pooled rows m in [3,60] need t3[m-1..m+1] in [2,61]. OK.
// ---------------------------------------------------------------------------
__global__ __launch_bounds__(256) void fused_kernel(
    const float* __restrict__ x,
    const float* __restrict__ enc_w1, const float* __restrict__ enc_b1,
    const short* __restrict__ Wf, const float* __restrict__ bp,
    const float* __restrict__ gc2_b, const float* __restrict__ gc3_b,
    float* __restrict__ partial, unsigned* __restrict__ cnt,
    const float* __restrict__ cls_w1, const float* __restrict__ cls_b1,
    const float* __restrict__ cls_w2, const float* __restrict__ cls_b2,
    float* __restrict__ out)
{
  __shared__ float hT[HID * MSTR];      // 34304 B, [k][slot]
  __shared__ float wsmall[7 * HID];     // enc_w1 (6x128) + enc_b1
  __shared__ float psum[256];
  __shared__ int lastf;

  const int tid  = threadIdx.x;
  const int lane = tid & 63;
  const int w    = tid >> 6;            // wave id 0..3
  const int gxb  = blockIdx.x, b = blockIdx.y;
  const int s0   = gxb * TILE;
  const bf16x8* Bf = (const bf16x8*)Wf;

  // ---------------- enc1 (fp32 VALU): lane = row m, wave = 32-col group ----
  for (int f = tid; f < 7 * HID; f += 256)
    wsmall[f] = (f < 6 * HID) ? enc_w1[f] : enc_b1[f - 6 * HID];

  const int sm = s0 - 3 + lane;
  float xv[6];
  if (sm >= 0 && sm < SEQ) {
    const f2* xp = (const f2*)(x + ((long long)b * SEQ + sm) * 6);
    const f2 a0 = xp[0], a1 = xp[1], a2 = xp[2];
    xv[0] = a0.x; xv[1] = a0.y; xv[2] = a1.x;
    xv[3] = a1.y; xv[4] = a2.x; xv[5] = a2.y;
  } else {
    #pragma unroll
    for (int k = 0; k < 6; ++k) xv[k] = 0.f;
  }
  __syncthreads();
  {
    const int c0 = w * 32;
    float4 a4[8];
    #pragma unroll
    for (int q = 0; q < 8; ++q) a4[q] = make_float4(0.f, 0.f, 0.f, 0.f);
    #pragma unroll
    for (int k = 0; k < 6; ++k) {
      #pragma unroll
      for (int q = 0; q < 8; ++q) {
        const float4 wv = *(const float4*)&wsmall[k * HID + c0 + q * 4];
        a4[q].x = fmaf(xv[k], wv.x, a4[q].x);
        a4[q].y = fmaf(xv[k], wv.y, a4[q].y);
        a4[q].z = fmaf(xv[k], wv.z, a4[q].z);
        a4[q].w = fmaf(xv[k], wv.w, a4[q].w);
      }
    }
    #pragma unroll
    for (int q = 0; q < 8; ++q) {
      const float4 bb = *(const float4*)&wsmall[6 * HID + c0 + q * 4];
      const int c = c0 + q * 4;
      hT[(c + 0) * MSTR + SLOT(lane)] = fmaxf(a4[q].x + bb.x, 0.f);
      hT[(c + 1) * MSTR + SLOT(lane)] = fmaxf(a4[q].y + bb.y, 0.f);
      hT[(c + 2) * MSTR + SLOT(lane)] = fmaxf(a4[q].z + bb.z, 0.f);
      hT[(c + 3) * MSTR + SLOT(lane)] = fmaxf(a4[q].w + bb.w, 0.f);
    }
  }
  // zero the guard slots (0 and 65) of every k-row — read by halo rows only,
  // but must be finite to avoid NaN propagation from uninitialized LDS.
  if (tid < 128) {
    hT[tid * MSTR + 0]  = 0.f;
    hT[tid * MSTR + 65] = 0.f;
  }
  __syncthreads();

  // ---------------- 3 MFMA layers ----------------
  const int mt   = w * 16 + (lane & 15);       // A-frag target row
  const int koct = (lane >> 4) * 8;            // A-frag k-octet base
  const int stt  = s0 - 3 + mt;
  const float invdA = (stt == 0 || stt == SEQ - 1) ? (1.0f / (2.0f + 1e-8f))
                                                   : (1.0f / (3.0f + 1e-8f));

  #pragma unroll 1
  for (int L = 0; L < 3; ++L) {
    const bf16x8* BhL = Bf + L * 4096;
    const bf16x8* BlL = BhL + 2048;
    const float* bias = (L == 0) ? bp : (L == 1) ? gc2_b : gc3_b;

    f32x4 acc_[8];
    #pragma unroll
    for (int nt = 0; nt < 8; ++nt) acc_[nt] = (f32x4){0.f, 0.f, 0.f, 0.f};

    #pragma unroll 1
    for (int ks = 0; ks < 4; ++ks) {
      // B-frags first (VMEM latency hides behind A assembly)
      const int fb = ks * 512 + lane;
      bf16x8 bh[8], bl[8];
      #pragma unroll
      for (int nt = 0; nt < 8; ++nt) {
        bh[nt] = BhL[fb + nt * 64];
        bl[nt] = BlL[fb + nt * 64];
      }
      // A-frag: read hT (agg+relu for L>0; uniform base+{0,4,8} neighbor
      // reads thanks to the guard-slot layout), cvt_pk pair-split hi/lo
      bf16x8 ah, al;
      {
        // base points at slot mt = row mt-1; +1 = row mt; +2 = row mt+1
        const float* pa = &hT[(ks * 32 + koct) * MSTR + mt];
        float v[8];
        #pragma unroll
        for (int j = 0; j < 8; ++j) {
          if (L == 0) {
            v[j] = pa[j * MSTR + 1];
          } else {
            const float t = (pa[j * MSTR] + pa[j * MSTR + 1] +
                             pa[j * MSTR + 2]) * invdA;
            v[j] = fmaxf(t, 0.f);
          }
        }
        u32x4 hv, lv;
        #pragma unroll
        for (int q = 0; q < 4; ++q) {
          const unsigned hp = cvt_pk_bf16(v[2 * q], v[2 * q + 1]);
          const float h0 = __uint_as_float(hp << 16);
          const float h1 = __uint_as_float(hp & 0xffff0000u);
          hv[q] = hp;
          lv[q] = cvt_pk_bf16(v[2 * q] - h0, v[2 * q + 1] - h1);
        }
        ah = __builtin_bit_cast(bf16x8, hv);
        al = __builtin_bit_cast(bf16x8, lv);
      }
      #pragma unroll
      for (int nt = 0; nt < 8; ++nt) {
        acc_[nt] = __builtin_amdgcn_mfma_f32_16x16x32_bf16(ah, bh[nt], acc_[nt], 0, 0, 0);
        acc_[nt] = __builtin_amdgcn_mfma_f32_16x16x32_bf16(ah, bl[nt], acc_[nt], 0, 0, 0);
        acc_[nt] = __builtin_amdgcn_mfma_f32_16x16x32_bf16(al, bh[nt], acc_[nt], 0, 0, 0);
      }
    }
    __syncthreads();   // all hT reads of this layer done

    // epilogue: t = inseq ? acc + bias : 0 -> hT[n][slot(m)] (C/D scatter)
    {
      const int n0 = lane & 15;
      const int mrow0 = w * 16 + (lane >> 4) * 4;
      #pragma unroll
      for (int nt = 0; nt < 8; ++nt) {
        const float bn = bias[nt * 16 + n0];
        float* pw = &hT[(nt * 16 + n0) * MSTR];
        #pragma unroll
        for (int r = 0; r < 4; ++r) {
          const int m = mrow0 + r;
          const int s = s0 - 3 + m;
          const bool vld = (s >= 0 && s < SEQ);
          pw[SLOT(m)] = vld ? (acc_[nt][r] + bn) : 0.f;
        }
      }
    }
    __syncthreads();   // publish t for next layer / pool
  }

  // ---------------- pool: h3 = relu(agg(t3)); sum owned rows ----------------
  {
    const int c = tid & 127, half = tid >> 7;
    float ps = 0.f;
    const float* pc = &hT[c * MSTR];
    #pragma unroll 1
    for (int r = 0; r < 29; ++r) {
      const int m = 3 + half * 29 + r;
      const int s = s0 + half * 29 + r;
      if (s < SEQ) {
        const float invd = (s == 0 || s == SEQ - 1) ? (1.0f / (2.0f + 1e-8f))
                                                    : (1.0f / (3.0f + 1e-8f));
        // t3[m-1..m+1] live at slots m, m+1, m+2
        ps += fmaxf((pc[m] + pc[m + 1] + pc[m + 2]) * invd, 0.f);
      }
    }
    psum[tid] = ps;
  }
  __syncthreads();

  // ---------------- publish partial (agent-scope stores, no contention) ----
  if (tid < 128) {
    __hip_atomic_store(&partial[((long long)b * GX + gxb) * HID + tid],
                       psum[tid] + psum[tid + 128],
                       __ATOMIC_RELAXED, __HIP_MEMORY_SCOPE_AGENT);
  }
  // each thread drains its own store acks (coherent point) before barrier
  asm volatile("s_waitcnt vmcnt(0)" ::: "memory");
  __syncthreads();
  if (tid == 0) {
    // RELAXED on purpose — see header comment (no L2 writeback/invalidate).
    const unsigned old = __hip_atomic_fetch_add(&cnt[b], 1u, __ATOMIC_RELAXED,
                                                __HIP_MEMORY_SCOPE_AGENT);
    lastf = (old == GX - 1) ? 1 : 0;
  }
  __syncthreads();
  if (!lastf) return;

  // ---------------- classifier (last block of batch b only) ----------------
  if (tid < 128) {
    float a = 0.f;
    #pragma unroll
    for (int g = 0; g < GX; ++g)
      a += __hip_atomic_load(&partial[((long long)b * GX + g) * HID + tid],
                             __ATOMIC_RELAXED, __HIP_MEMORY_SCOPE_AGENT);
    psum[tid] = a * (1.0f / 2048.0f);
  }
  __syncthreads();
  if (tid < 64) {
    float h = cls_b1[tid];
    for (int k = 0; k < 128; ++k) h = fmaf(psum[k], cls_w1[k * 64 + tid], h);
    psum[128 + tid] = fmaxf(h, 0.f);
  }
  __syncthreads();
  if (tid < 3) {
    float o = cls_b2[tid];
    for (int k = 0; k < 64; ++k) o = fmaf(psum[128 + k], cls_w2[k * 3 + tid], o);
    out[b * 3 + tid] = o;
  }
}

extern "C" void kernel_launch(void* const* d_in, const int* in_sizes, int n_in,
                              void* d_out, int out_size, void* d_ws, size_t ws_size,
                              hipStream_t stream) {
  (void)in_sizes; (void)n_in; (void)out_size; (void)ws_size;
  const float* x      = (const float*)d_in[0];
  const float* enc_w1 = (const float*)d_in[1];
  const float* enc_b1 = (const float*)d_in[2];
  const float* enc_w2 = (const float*)d_in[3];
  const float* enc_b2 = (const float*)d_in[4];
  const float* gc1_w  = (const float*)d_in[5];
  const float* gc1_b  = (const float*)d_in[6];
  const float* gc2_w  = (const float*)d_in[7];
  const float* gc2_b  = (const float*)d_in[8];
  const float* gc3_w  = (const float*)d_in[9];
  const float* gc3_b  = (const float*)d_in[10];
  const float* cls_w1 = (const float*)d_in[11];
  const float* cls_b1 = (const float*)d_in[12];
  const float* cls_w2 = (const float*)d_in[13];
  const float* cls_b2 = (const float*)d_in[14];

  // workspace layout (rewritten fully every launch — ws is re-poisoned)
  float* bpv     = (float*)d_ws;                     // 128 f32
  short* Wfrag   = (short*)(bpv + 128);              // 3 * 2 * 16384 bf16
  float* partial = (float*)(Wfrag + 3 * 2 * 16384);  // NB*GX*HID f32 (all slots rewritten)
  unsigned* cntb = (unsigned*)(partial + (long long)NB * GX * HID);  // NB u32 (zeroed by prep)

  prep_kernel<<<dim3(97), 256, 0, stream>>>(enc_w2, enc_b2, gc1_w, gc1_b,
                                            gc2_w, gc3_w, Wfrag, bpv, cntb);
  fused_kernel<<<dim3(GX, NB), 256, 0, stream>>>(
      x, enc_w1, enc_b1, Wfrag, bpv, gc2_b, gc3_b, partial, cntb,
      cls_w1, cls_b1, cls_w2, cls_b2, (float*)d_out);
}